// Round 7
// baseline (996.922 us; speedup 1.0000x reference)
//
#include <hip/hip_runtime.h>
#include <math.h>

// Problem constants
constexpr int Bb = 4;
constexpr int Tt = 2048;
constexpr int Cc = 1024;
constexpr int Hh = 16;
constexpr int Dh = 64;
constexpr int Mm = Bb * Tt;  // 8192

typedef __attribute__((ext_vector_type(8))) short s16x8;   // bf16x8 frag (4 VGPR)
typedef __attribute__((ext_vector_type(4))) short s16x4;
typedef __attribute__((ext_vector_type(4))) float f32x4;

// fp32 -> bf16 round-to-nearest-even (bit pattern)
__device__ __forceinline__ unsigned short f2bf(float x) {
    unsigned u = __float_as_uint(x);
    u += 0x7FFFu + ((u >> 16) & 1u);
    return (unsigned short)(u >> 16);
}
__device__ __forceinline__ float bf2f(unsigned short h) {
    return __uint_as_float((unsigned)h << 16);
}

__device__ __forceinline__ void gld16(const void* g, void* l) {
    __builtin_amdgcn_global_load_lds(
        (const __attribute__((address_space(1))) void*)g,
        (__attribute__((address_space(3))) void*)l, 16, 0, 0);
}

// ---------------------------------------------------------------------------
// Split-bf16 "conv" layout: logical [row][K/32 groups][8 slots][16B].
// Slot s: s=0..3 -> h of octet s; s=4..7 -> l of octet s-4.
// Staged into LDS with XOR swizzle on the GLOBAL source (phys slot p holds
// logical p^(r&7)); ds_read applies the matching XOR. Bank-conflict-free
// (r6 counters: SQ_LDS_BANK_CONFLICT = 0).
// ---------------------------------------------------------------------------

// ---------------------------------------------------------------------------
// LayerNorm -> conv layout. One block per row, 256 threads x float4.
// ---------------------------------------------------------------------------
__global__ __launch_bounds__(256) void ln_conv_kernel(const float* __restrict__ in,
                                                      char* __restrict__ out) {
    const int row = blockIdx.x;
    const float4 v = reinterpret_cast<const float4*>(in + (size_t)row * Cc)[threadIdx.x];
    float s = v.x + v.y + v.z + v.w;
    float q = v.x * v.x + v.y * v.y + v.z * v.z + v.w * v.w;
#pragma unroll
    for (int off = 32; off > 0; off >>= 1) {
        s += __shfl_xor(s, off);
        q += __shfl_xor(q, off);
    }
    __shared__ float red[2][4];
    const int wid = threadIdx.x >> 6;
    if ((threadIdx.x & 63) == 0) { red[0][wid] = s; red[1][wid] = q; }
    __syncthreads();
    s = red[0][0] + red[0][1] + red[0][2] + red[0][3];
    q = red[1][0] + red[1][1] + red[1][2] + red[1][3];
    const float mean = s * (1.0f / Cc);
    const float var = q * (1.0f / Cc) - mean * mean;
    const float rstd = rsqrtf(var + 1e-10f);
    float o[4] = {(v.x - mean) * rstd, (v.y - mean) * rstd,
                  (v.z - mean) * rstd, (v.w - mean) * rstd};
    s16x4 hv, lv;
#pragma unroll
    for (int j = 0; j < 4; ++j) {
        unsigned short h = f2bf(o[j]);
        hv[j] = (short)h;
        lv[j] = (short)f2bf(o[j] - bf2f(h));
    }
    const int c0 = threadIdx.x * 4;
    char* p = out + (size_t)row * 4096 + ((c0 >> 5) * 8 + ((c0 >> 3) & 3)) * 16 + (c0 & 7) * 2;
    *reinterpret_cast<s16x4*>(p) = hv;
    *reinterpret_cast<s16x4*>(p + 64) = lv;
}

// ---------------------------------------------------------------------------
// Weight fp32 [N rows][K cols, stride ldk] -> conv layout. Thread per octet.
// ---------------------------------------------------------------------------
__global__ __launch_bounds__(256) void wconv_kernel(const float* __restrict__ W,
                                                    char* __restrict__ out,
                                                    int noct, int oshift, int ldk) {
    const int idx = blockIdx.x * 256 + threadIdx.x;
    if (idx >= noct) return;
    const int r = idx >> oshift;
    const int oct = idx & ((1 << oshift) - 1);
    const float* p = W + (size_t)r * ldk + oct * 8;
    float4 a = *reinterpret_cast<const float4*>(p);
    float4 b = *reinterpret_cast<const float4*>(p + 4);
    float xs[8] = {a.x, a.y, a.z, a.w, b.x, b.y, b.z, b.w};
    s16x8 hv, lv;
#pragma unroll
    for (int j = 0; j < 8; ++j) {
        unsigned short h = f2bf(xs[j]);
        hv[j] = (short)h;
        lv[j] = (short)f2bf(xs[j] - bf2f(h));
    }
    const int Kg = 1 << (oshift - 2);
    char* o = out + (((size_t)r * Kg + (oct >> 2)) * 8 + (oct & 3)) * 16;
    *reinterpret_cast<s16x8*>(o) = hv;
    *reinterpret_cast<s16x8*>(o + 64) = lv;
}

// ---------------------------------------------------------------------------
// 256x256 8-phase split-bf16 MFMA GEMM (T1+T2+T3+T4+T5).
// BK=32 (one conv group), 512 thr / 8 waves (2Mx4N), wave tile 128x64.
// LDS 128KB = 2 buf x (A 32K + B 32K). Per K-tile: 4 phases (m-frag pairs);
// phase 0 also reads all B-frags and issues the 8 next-tile global_load_lds;
// single vmcnt(0) per K-tile at phase 3. Raw s_barrier + asm waits (no
// __syncthreads: it would drain vmcnt every phase).
// ---------------------------------------------------------------------------
__device__ __forceinline__ float gelu_f(float v) {
    const float z = 1.5957691216057308f * (v + 0.044715f * v * v * v);
    return v / (1.0f + __expf(-z));
}

template <bool GELU, bool RESID, bool CONVOUT, bool ADDBIAS>
__global__ __launch_bounds__(512, 2) void gemm_mfma8(
    const char* __restrict__ Ac, const char* __restrict__ Bc,
    const float* __restrict__ bias, const float* __restrict__ resid,
    float* __restrict__ Cout, char* __restrict__ Cconv,
    int M, int N, int K) {
    const int tid = threadIdx.x;
    const int lane = tid & 63;
    const int wid = tid >> 6;
    // T1: bijective XCD swizzle (all our grids have nwg % 8 == 0)
    const int gx = gridDim.x;
    const int nwg = gx * gridDim.y;
    int flat = blockIdx.y * gx + blockIdx.x;
    flat = (flat & 7) * (nwg >> 3) + (flat >> 3);
    const int bn = (flat % gx) * 256;
    const int bm = (flat / gx) * 256;
    const int wm = (wid >> 2) * 128;   // 2 wave-rows of 128
    const int wn = (wid & 3) * 64;     // 4 wave-cols of 64
    const int Kg = K >> 5;             // K-tiles (= conv groups)

    __shared__ char lds[131072];

    f32x4 acc[8][4];
#pragma unroll
    for (int i = 0; i < 8; ++i)
#pragma unroll
        for (int j = 0; j < 4; ++j) acc[i][j] = (f32x4)0.0f;

    // staging per-thread constants: unit u covers phys (row u>>3, slot u&7)
    unsigned int aoff[4], boff[4], ldso[4];
#pragma unroll
    for (int i = 0; i < 4; ++i) {
        const int u = tid + i * 512;
        const int r = u >> 3;
        const int s = (u & 7) ^ (r & 7);   // logical slot at this phys slot
        aoff[i] = (unsigned int)((bm + r) * Kg * 128 + s * 16);
        boff[i] = (unsigned int)((bn + r) * Kg * 128 + s * 16);
        ldso[i] = (unsigned int)(u * 16);
    }

    // frag ds_read byte offsets (h; l at ^64)
    const int g = lane >> 4, fr = lane & 15;
    unsigned int afo[8], bfo[4];
#pragma unroll
    for (int i = 0; i < 8; ++i) {
        const int ra = wm + i * 16 + fr;
        afo[i] = (unsigned int)(ra * 128 + ((g ^ (ra & 7)) << 4));
    }
#pragma unroll
    for (int j = 0; j < 4; ++j) {
        const int rb = wn + j * 16 + fr;
        bfo[j] = (unsigned int)(rb * 128 + ((g ^ (rb & 7)) << 4));
    }

    auto stage = [&](int tt, int buf) {
        char* Ad = lds + buf * 65536;
        char* Bd = Ad + 32768;
        const unsigned int tb = (unsigned int)tt * 128;
#pragma unroll
        for (int i = 0; i < 4; ++i) gld16(Ac + aoff[i] + tb, Ad + ldso[i]);
#pragma unroll
        for (int i = 0; i < 4; ++i) gld16(Bc + boff[i] + tb, Bd + ldso[i]);
    };

    // prologue: stage K-tile 0 into buf 0
    stage(0, 0);
    asm volatile("s_waitcnt vmcnt(0)" ::: "memory");
    __builtin_amdgcn_s_barrier();

    s16x8 Bh[4], Bl[4];
    for (int t = 0; t < Kg; ++t) {
        const int c = t & 1;
        const char* Ab = lds + c * 65536;
        const char* Bb = Ab + 32768;
#pragma unroll
        for (int q = 0; q < 4; ++q) {
            if (q == 0) {
#pragma unroll
                for (int j = 0; j < 4; ++j) {
                    Bh[j] = *reinterpret_cast<const s16x8*>(Bb + bfo[j]);
                    Bl[j] = *reinterpret_cast<const s16x8*>(Bb + (bfo[j] ^ 64u));
                }
            }
            const s16x8 Ah0 = *reinterpret_cast<const s16x8*>(Ab + afo[2 * q]);
            const s16x8 Al0 = *reinterpret_cast<const s16x8*>(Ab + (afo[2 * q] ^ 64u));
            const s16x8 Ah1 = *reinterpret_cast<const s16x8*>(Ab + afo[2 * q + 1]);
            const s16x8 Al1 = *reinterpret_cast<const s16x8*>(Ab + (afo[2 * q + 1] ^ 64u));
            if (q == 0 && t + 1 < Kg) stage(t + 1, c ^ 1);
            __builtin_amdgcn_s_barrier();
            asm volatile("s_waitcnt lgkmcnt(0)" ::: "memory");
            __builtin_amdgcn_sched_barrier(0);
            __builtin_amdgcn_s_setprio(1);
#pragma unroll
            for (int j = 0; j < 4; ++j) {
                acc[2 * q][j] = __builtin_amdgcn_mfma_f32_16x16x32_bf16(Ah0, Bh[j], acc[2 * q][j], 0, 0, 0);
                acc[2 * q][j] = __builtin_amdgcn_mfma_f32_16x16x32_bf16(Al0, Bh[j], acc[2 * q][j], 0, 0, 0);
                acc[2 * q][j] = __builtin_amdgcn_mfma_f32_16x16x32_bf16(Ah0, Bl[j], acc[2 * q][j], 0, 0, 0);
                acc[2 * q + 1][j] = __builtin_amdgcn_mfma_f32_16x16x32_bf16(Ah1, Bh[j], acc[2 * q + 1][j], 0, 0, 0);
                acc[2 * q + 1][j] = __builtin_amdgcn_mfma_f32_16x16x32_bf16(Al1, Bh[j], acc[2 * q + 1][j], 0, 0, 0);
                acc[2 * q + 1][j] = __builtin_amdgcn_mfma_f32_16x16x32_bf16(Ah1, Bl[j], acc[2 * q + 1][j], 0, 0, 0);
            }
            __builtin_amdgcn_s_setprio(0);
            __builtin_amdgcn_sched_barrier(0);
            if (q == 3) asm volatile("s_waitcnt vmcnt(0)" ::: "memory");
            __builtin_amdgcn_s_barrier();
        }
    }

    // epilogue: D row = (lane>>4)*4 + reg, col = lane&15 (validated r5/r6)
    float bcol[4];
#pragma unroll
    for (int j = 0; j < 4; ++j)
        bcol[j] = ADDBIAS ? bias[bn + wn + j * 16 + fr] : 0.0f;

#pragma unroll
    for (int i = 0; i < 8; ++i) {
#pragma unroll
        for (int rr = 0; rr < 4; ++rr) {
            const int row = bm + wm + i * 16 + g * 4 + rr;
#pragma unroll
            for (int j = 0; j < 4; ++j) {
                const int col = bn + wn + j * 16 + fr;
                float v = acc[i][j][rr] + bcol[j];
                if (RESID) v += resid[(size_t)row * N + col];
                if (GELU) v = gelu_f(v);
                if (!CONVOUT) {
                    Cout[(size_t)row * N + col] = v;
                } else {
                    const unsigned short h = f2bf(v);
                    const unsigned short l = f2bf(v - bf2f(h));
                    char* p = Cconv +
                              (((size_t)row * (N >> 5) + (col >> 5)) * 8 + ((col >> 3) & 3)) * 16 +
                              (col & 7) * 2;
                    *reinterpret_cast<unsigned short*>(p) = h;
                    *reinterpret_cast<unsigned short*>(p + 64) = l;
                }
            }
        }
    }
}

// ---------------------------------------------------------------------------
// qkv fp32 [B*T][3C] -> bf16 buffers: qb/kb [bh][T][64] (q pre-scaled 1/8),
// vt [bh][64][T] (transposed via LDS). Grid (T/64, B*H), 256 threads.
// ---------------------------------------------------------------------------
__global__ __launch_bounds__(256) void qkv_repack_kernel(
    const float* __restrict__ qkv, unsigned short* __restrict__ qb,
    unsigned short* __restrict__ kb, unsigned short* __restrict__ vtb) {
    const int bh = blockIdx.y;
    const int b = bh >> 4, h = bh & 15;
    const int t0 = blockIdx.x * 64;
    const int tid = threadIdx.x;
    __shared__ unsigned short vtile[64][66];
#pragma unroll
    for (int r = 0; r < 16; ++r) {
        const int idx = tid + r * 256;
        const int t = idx >> 6, d = idx & 63;
        const size_t src = (size_t)(b * Tt + t0 + t) * 3072 + h * 64 + d;
        const size_t dst = ((size_t)bh * Tt + t0 + t) * 64 + d;
        qb[dst] = f2bf(qkv[src] * 0.125f);
        kb[dst] = f2bf(qkv[src + 1024]);
        vtile[t][d] = f2bf(qkv[src + 2048]);
    }
    __syncthreads();
#pragma unroll
    for (int r = 0; r < 16; ++r) {
        const int idx = tid + r * 256;
        const int d = idx >> 6, t = idx & 63;
        vtb[((size_t)bh * 64 + d) * Tt + t0 + t] = vtile[t][d];
    }
}

// ---------------------------------------------------------------------------
// MFMA flash attention (validated r6). Grid (T/64, B*H), 256 threads.
// ---------------------------------------------------------------------------
__global__ __launch_bounds__(256) void attn_mfma_kernel(
    const unsigned short* __restrict__ qbuf, const unsigned short* __restrict__ kbuf,
    const unsigned short* __restrict__ vtbuf, char* __restrict__ yconv) {
    const int qt = blockIdx.x;
    const int bh = blockIdx.y;
    const int tid = threadIdx.x;
    const int w = tid >> 6, lane = tid & 63;
    const int g = lane >> 4, fr = lane & 15;
    const int qbase = qt * 64;

    const unsigned short* Q  = qbuf  + (size_t)bh * Tt * 64;
    const unsigned short* K  = kbuf  + (size_t)bh * Tt * 64;
    const unsigned short* Vt = vtbuf + (size_t)bh * 64 * Tt;

    __shared__ unsigned short Kl[64][72];
    __shared__ unsigned short Vl[64][72];
    __shared__ unsigned short Pl[4][16][72];

    s16x8 qf[2];
#pragma unroll
    for (int s = 0; s < 2; ++s)
        qf[s] = *reinterpret_cast<const s16x8*>(
            &Q[(size_t)(qbase + 16 * w + fr) * 64 + s * 32 + 8 * g]);

    f32x4 acc_o[4];
#pragma unroll
    for (int jd = 0; jd < 4; ++jd) acc_o[jd] = (f32x4)0.0f;
    float lpart[4] = {0.f, 0.f, 0.f, 0.f};

    for (int t0 = 0; t0 <= qt; ++t0) {
        __syncthreads();
#pragma unroll
        for (int r2 = 0; r2 < 2; ++r2) {
            const int idx = tid + r2 * 256;
            const int row = idx >> 3, c = idx & 7;
            *reinterpret_cast<s16x8*>(&Kl[row][c * 8]) =
                *reinterpret_cast<const s16x8*>(&K[(size_t)(t0 * 64 + row) * 64 + c * 8]);
            *reinterpret_cast<s16x8*>(&Vl[row][c * 8]) =
                *reinterpret_cast<const s16x8*>(&Vt[(size_t)row * Tt + t0 * 64 + c * 8]);
        }
        __syncthreads();

        f32x4 acc_s[4];
#pragma unroll
        for (int jk = 0; jk < 4; ++jk) acc_s[jk] = (f32x4)0.0f;
#pragma unroll
        for (int s = 0; s < 2; ++s)
#pragma unroll
            for (int jk = 0; jk < 4; ++jk) {
                const s16x8 kf = *reinterpret_cast<const s16x8*>(
                    &Kl[16 * jk + fr][s * 32 + 8 * g]);
                acc_s[jk] = __builtin_amdgcn_mfma_f32_16x16x32_bf16(qf[s], kf, acc_s[jk], 0, 0, 0);
            }

        const bool diag = (t0 == qt);
#pragma unroll
        for (int jk = 0; jk < 4; ++jk)
#pragma unroll
            for (int rr = 0; rr < 4; ++rr) {
                const int key = 16 * jk + fr;
                const int qrow = 16 * w + 4 * g + rr;
                float p = __expf(acc_s[jk][rr]);
                if (diag && key > qrow) p = 0.0f;
                lpart[rr] += p;
                Pl[w][4 * g + rr][key] = f2bf(p);
            }

#pragma unroll
        for (int s = 0; s < 2; ++s) {
            const s16x8 pf = *reinterpret_cast<const s16x8*>(&Pl[w][fr][s * 32 + 8 * g]);
#pragma unroll
            for (int jd = 0; jd < 4; ++jd) {
                const s16x8 vf = *reinterpret_cast<const s16x8*>(
                    &Vl[16 * jd + fr][s * 32 + 8 * g]);
                acc_o[jd] = __builtin_amdgcn_mfma_f32_16x16x32_bf16(pf, vf, acc_o[jd], 0, 0, 0);
            }
        }
    }

#pragma unroll
    for (int rr = 0; rr < 4; ++rr) {
#pragma unroll
        for (int off = 1; off < 16; off <<= 1)
            lpart[rr] += __shfl_xor(lpart[rr], off);
    }
    float inv[4];
#pragma unroll
    for (int rr = 0; rr < 4; ++rr) inv[rr] = 1.0f / lpart[rr];

    const int bq = bh >> 4;
#pragma unroll
    for (int rr = 0; rr < 4; ++rr) {
        const int row = bq * Tt + qbase + 16 * w + 4 * g + rr;
#pragma unroll
        for (int jd = 0; jd < 4; ++jd) {
            const int col = (bh & 15) * Dh + 16 * jd + fr;
            const float v = acc_o[jd][rr] * inv[rr];
            const unsigned short h = f2bf(v);
            const unsigned short l = f2bf(v - bf2f(h));
            char* p = yconv + (((size_t)row * (Cc >> 5) + (col >> 5)) * 8 + ((col >> 3) & 3)) * 16 +
                      (col & 7) * 2;
            *reinterpret_cast<unsigned short*>(p) = h;
            *reinterpret_cast<unsigned short*>(p + 64) = l;
        }
    }
}

// ---------------------------------------------------------------------------
// Workspace (176 MB, guarded) — unchanged from r6.
// ---------------------------------------------------------------------------
extern "C" void kernel_launch(void* const* d_in, const int* in_sizes, int n_in,
                              void* d_out, int out_size, void* d_ws,
                              size_t ws_size, hipStream_t stream) {
    const float* x      = (const float*)d_in[0];
    const float* w_attn = (const float*)d_in[1];
    const float* b_attn = (const float*)d_in[2];
    const float* w_proj = (const float*)d_in[3];
    const float* b_proj = (const float*)d_in[4];
    const float* w_fc   = (const float*)d_in[5];
    const float* b_fc   = (const float*)d_in[6];
    const float* w_mlp  = (const float*)d_in[7];
    const float* b_mlp  = (const float*)d_in[8];
    float* out = (float*)d_out;

    if (ws_size < (176ull << 20)) return;

    char* ws = (char*)d_ws;
    char*  slotbuf = ws;                                         // 32MB
    float* qkv     = (float*)(ws + (32ull << 20));               // 96MB
    char*  hconv   = ws + (32ull << 20);                         // 128MB overlay
    unsigned short* qb = (unsigned short*)(ws + (128ull << 20)); // 16MB
    unsigned short* kb = (unsigned short*)(ws + (144ull << 20)); // 16MB
    unsigned short* vt = (unsigned short*)(ws + (160ull << 20)); // 16MB
    char*  wscr    = ws + (160ull << 20);                        // 16MB (time-shared with vt)
    float* x1      = out;

    // 1. ln1 -> slotbuf
    ln_conv_kernel<<<Mm, 256, 0, stream>>>(x, slotbuf);
    // 2. qkv = ln1 @ w_attn^T + b_attn (fp32)
    wconv_kernel<<<1536, 256, 0, stream>>>(w_attn, wscr, 3072 * 128, 7, 1024);
    gemm_mfma8<false, false, false, true><<<dim3(12, 32), 512, 0, stream>>>(
        slotbuf, wscr, b_attn, nullptr, qkv, nullptr, Mm, 3 * Cc, Cc);
    // 3. repack qkv -> qb/kb/vt
    qkv_repack_kernel<<<dim3(Tt / 64, Bb * Hh), 256, 0, stream>>>(qkv, qb, kb, vt);
    // 4. attention -> slotbuf (conv)
    attn_mfma_kernel<<<dim3(Tt / 64, Bb * Hh), 256, 0, stream>>>(qb, kb, vt, slotbuf);
    // 5. x1 = x + y @ w_proj^T + b_proj
    wconv_kernel<<<512, 256, 0, stream>>>(w_proj, wscr, 1024 * 128, 7, 1024);
    gemm_mfma8<false, true, false, true><<<dim3(4, 32), 512, 0, stream>>>(
        slotbuf, wscr, b_proj, x, x1, nullptr, Mm, Cc, Cc);
    // 6. ln2 -> slotbuf
    ln_conv_kernel<<<Mm, 256, 0, stream>>>(x1, slotbuf);
    // 7. hconv = gelu(ln2 @ w_fc^T + b_fc)
    wconv_kernel<<<2048, 256, 0, stream>>>(w_fc, wscr, 4096 * 128, 7, 1024);
    gemm_mfma8<true, false, true, true><<<dim3(16, 32), 512, 0, stream>>>(
        slotbuf, wscr, b_fc, nullptr, nullptr, hconv, Mm, 4 * Cc, Cc);
    // 8. out = x1 + h @ w_mlp^T + b_mlp
    wconv_kernel<<<2048, 256, 0, stream>>>(w_mlp, wscr, 1024 * 512, 9, 4096);
    gemm_mfma8<false, true, false, true><<<dim3(4, 32), 512, 0, stream>>>(
        hconv, wscr, b_mlp, x1, out, nullptr, Mm, Cc, 4 * Cc);
}

// Round 9
// 922.465 us; speedup vs baseline: 1.0807x; 1.0807x over previous
//
#include <hip/hip_runtime.h>
#include <math.h>

// Problem constants
constexpr int Bb = 4;
constexpr int Tt = 2048;
constexpr int Cc = 1024;
constexpr int Hh = 16;
constexpr int Dh = 64;
constexpr int Mm = Bb * Tt;  // 8192

typedef __attribute__((ext_vector_type(8))) short s16x8;   // bf16x8 frag (4 VGPR)
typedef __attribute__((ext_vector_type(4))) short s16x4;
typedef __attribute__((ext_vector_type(4))) float f32x4;

// fp32 -> bf16 round-to-nearest-even (bit pattern)
__device__ __forceinline__ unsigned short f2bf(float x) {
    unsigned u = __float_as_uint(x);
    u += 0x7FFFu + ((u >> 16) & 1u);
    return (unsigned short)(u >> 16);
}
__device__ __forceinline__ float bf2f(unsigned short h) {
    return __uint_as_float((unsigned)h << 16);
}

__device__ __forceinline__ void gld16(const void* g, void* l) {
    __builtin_amdgcn_global_load_lds(
        (const __attribute__((address_space(1))) void*)g,
        (__attribute__((address_space(3))) void*)l, 16, 0, 0);
}

// ---------------------------------------------------------------------------
// Split-bf16 "conv" layout: logical [row][K/32 groups][8 slots][16B].
// Slot s: s=0..3 -> h of octet s; s=4..7 -> l of octet s-4. Staged into LDS
// with XOR swizzle on the GLOBAL source (phys slot p holds logical p^(r&7));
// ds_read applies the matching XOR. Bank-conflict-free (r6: conflicts = 0).
// ---------------------------------------------------------------------------

// ---------------------------------------------------------------------------
// LayerNorm -> conv layout. One block per row, 256 threads x float4.
// ---------------------------------------------------------------------------
__global__ __launch_bounds__(256) void ln_conv_kernel(const float* __restrict__ in,
                                                      char* __restrict__ out) {
    const int row = blockIdx.x;
    const float4 v = reinterpret_cast<const float4*>(in + (size_t)row * Cc)[threadIdx.x];
    float s = v.x + v.y + v.z + v.w;
    float q = v.x * v.x + v.y * v.y + v.z * v.z + v.w * v.w;
#pragma unroll
    for (int off = 32; off > 0; off >>= 1) {
        s += __shfl_xor(s, off);
        q += __shfl_xor(q, off);
    }
    __shared__ float red[2][4];
    const int wid = threadIdx.x >> 6;
    if ((threadIdx.x & 63) == 0) { red[0][wid] = s; red[1][wid] = q; }
    __syncthreads();
    s = red[0][0] + red[0][1] + red[0][2] + red[0][3];
    q = red[1][0] + red[1][1] + red[1][2] + red[1][3];
    const float mean = s * (1.0f / Cc);
    const float var = q * (1.0f / Cc) - mean * mean;
    const float rstd = rsqrtf(var + 1e-10f);
    float o[4] = {(v.x - mean) * rstd, (v.y - mean) * rstd,
                  (v.z - mean) * rstd, (v.w - mean) * rstd};
    s16x4 hv, lv;
#pragma unroll
    for (int j = 0; j < 4; ++j) {
        unsigned short h = f2bf(o[j]);
        hv[j] = (short)h;
        lv[j] = (short)f2bf(o[j] - bf2f(h));
    }
    const int c0 = threadIdx.x * 4;
    char* p = out + (size_t)row * 4096 + ((c0 >> 5) * 8 + ((c0 >> 3) & 3)) * 16 + (c0 & 7) * 2;
    *reinterpret_cast<s16x4*>(p) = hv;
    *reinterpret_cast<s16x4*>(p + 64) = lv;
}

// ---------------------------------------------------------------------------
// Weight fp32 [N rows][K cols, stride ldk] -> conv layout. Thread per octet.
// ---------------------------------------------------------------------------
__global__ __launch_bounds__(256) void wconv_kernel(const float* __restrict__ W,
                                                    char* __restrict__ out,
                                                    int noct, int oshift, int ldk) {
    const int idx = blockIdx.x * 256 + threadIdx.x;
    if (idx >= noct) return;
    const int r = idx >> oshift;
    const int oct = idx & ((1 << oshift) - 1);
    const float* p = W + (size_t)r * ldk + oct * 8;
    float4 a = *reinterpret_cast<const float4*>(p);
    float4 b = *reinterpret_cast<const float4*>(p + 4);
    float xs[8] = {a.x, a.y, a.z, a.w, b.x, b.y, b.z, b.w};
    s16x8 hv, lv;
#pragma unroll
    for (int j = 0; j < 8; ++j) {
        unsigned short h = f2bf(xs[j]);
        hv[j] = (short)h;
        lv[j] = (short)f2bf(xs[j] - bf2f(h));
    }
    const int Kg = 1 << (oshift - 2);
    char* o = out + (((size_t)r * Kg + (oct >> 2)) * 8 + (oct & 3)) * 16;
    *reinterpret_cast<s16x8*>(o) = hv;
    *reinterpret_cast<s16x8*>(o + 64) = lv;
}

// ---------------------------------------------------------------------------
// 256x128-tile split-bf16 MFMA GEMM with 3-buffer LDS pipeline and COUNTED
// vmcnt (T3+T4+T5+T1). BK=32 (one conv group), 512 thr / 8 waves (4M x 2N),
// wave tile 64x64, acc[4][4]. LDS = 3 x 48KB = 144KB (A 32K + B 16K per buf).
// Per K-tile: 4 phases (phase q = A-frag q x all B). Phases q0/q1/q2 each
// stage one half-tile (2 gld16/thread) of tile t+2 into buf (t+2)%3.
// Boundary: vmcnt(6) retires tile t+1's 6 loads (oldest; issued a full tile
// ago). Never drains to 0 in steady state (T4, m218). Rule-18 fence
// (sched_barrier after lgkmcnt asm) present.
// ---------------------------------------------------------------------------
__device__ __forceinline__ float gelu_f(float v) {
    const float z = 1.5957691216057308f * (v + 0.044715f * v * v * v);
    return v / (1.0f + __expf(-z));
}

template <bool GELU, bool RESID, bool CONVOUT, bool ADDBIAS>
__global__ __launch_bounds__(512, 2) void gemm_mfma8(
    const char* __restrict__ Ac, const char* __restrict__ Bc,
    const float* __restrict__ bias, const float* __restrict__ resid,
    float* __restrict__ Cout, char* __restrict__ Cconv,
    int M, int N, int K) {
    const int tid = threadIdx.x;
    const int lane = tid & 63;
    const int wid = tid >> 6;
    // T1: bijective XCD swizzle (all our grids have nwg % 8 == 0)
    const int gx = gridDim.x;
    const int nwg = gx * gridDim.y;
    int flat = blockIdx.y * gx + blockIdx.x;
    flat = (flat & 7) * (nwg >> 3) + (flat >> 3);
    const int bn = (flat % gx) * 128;
    const int bm = (flat / gx) * 256;
    const int wm = (wid >> 1) * 64;    // 4 wave-rows of 64
    const int wn = (wid & 1) * 64;     // 2 wave-cols of 64
    const int Kg = K >> 5;             // K-tiles (= conv groups)

    __shared__ char lds[147456];       // 3 bufs x (A 32768 + B 16384)

    f32x4 acc[4][4];
#pragma unroll
    for (int i = 0; i < 4; ++i)
#pragma unroll
        for (int j = 0; j < 4; ++j) acc[i][j] = (f32x4)0.0f;

    // Staging per-thread constants. A: 4 units (u=tid+i*512, r=u>>3 in 0..255)
    // B: 2 units (r in 0..127). Phys slot u&7 holds logical (u&7)^(r&7).
    unsigned int aoff[4], boff[2], ldsoA[4], ldsoB[2];
#pragma unroll
    for (int i = 0; i < 4; ++i) {
        const int u = tid + i * 512;
        const int r = u >> 3;
        const int s = (u & 7) ^ (r & 7);
        aoff[i] = (unsigned int)((bm + r) * Kg * 128 + s * 16);
        ldsoA[i] = (unsigned int)(u * 16);
    }
#pragma unroll
    for (int i = 0; i < 2; ++i) {
        const int u = tid + i * 512;
        const int r = u >> 3;
        const int s = (u & 7) ^ (r & 7);
        boff[i] = (unsigned int)((bn + r) * Kg * 128 + s * 16);
        ldsoB[i] = (unsigned int)(32768 + u * 16);
    }

    // frag ds_read byte offsets (h; l at ^64)
    const int g = lane >> 4, fr = lane & 15;
    unsigned int afo[4], bfo[4];
#pragma unroll
    for (int i = 0; i < 4; ++i) {
        const int ra = wm + i * 16 + fr;
        afo[i] = (unsigned int)(ra * 128 + ((g ^ (ra & 7)) << 4));
    }
#pragma unroll
    for (int j = 0; j < 4; ++j) {
        const int rb = wn + j * 16 + fr;
        bfo[j] = (unsigned int)(32768 + rb * 128 + ((g ^ (rb & 7)) << 4));
    }

    // Prologue: stage tiles 0 and 1 fully (12 loads), then wait tile 0 (keep
    // tile 1's 6 in flight) and sync.
    {
        char* d0 = lds;
        char* d1 = lds + 49152;
#pragma unroll
        for (int i = 0; i < 4; ++i) gld16(Ac + aoff[i], d0 + ldsoA[i]);
#pragma unroll
        for (int i = 0; i < 2; ++i) gld16(Bc + boff[i], d0 + ldsoB[i]);
        if (Kg > 1) {
#pragma unroll
            for (int i = 0; i < 4; ++i) gld16(Ac + aoff[i] + 128, d1 + ldsoA[i]);
#pragma unroll
            for (int i = 0; i < 2; ++i) gld16(Bc + boff[i] + 128, d1 + ldsoB[i]);
            asm volatile("s_waitcnt vmcnt(6)" ::: "memory");
        } else {
            asm volatile("s_waitcnt vmcnt(0)" ::: "memory");
        }
        __builtin_amdgcn_s_barrier();
    }

    int cbuf = 0;      // buf of tile t
    int sbuf = 2;      // buf of tile t+2
    for (int t = 0; t < Kg; ++t) {
        const char* Ab = lds + cbuf * 49152;
        const bool pf = (t + 2 < Kg);
        char* Sd = lds + sbuf * 49152;
        const unsigned int tb2 = (unsigned int)(t + 2) * 128;

        s16x8 Bh[4], Bl[4];
#pragma unroll
        for (int q = 0; q < 4; ++q) {
            // ---- ds_read this phase's fragments ----
            if (q == 0) {
#pragma unroll
                for (int j = 0; j < 4; ++j) {
                    Bh[j] = *reinterpret_cast<const s16x8*>(Ab + bfo[j]);
                    Bl[j] = *reinterpret_cast<const s16x8*>(Ab + (bfo[j] ^ 64u));
                }
            }
            const s16x8 Ah = *reinterpret_cast<const s16x8*>(Ab + afo[q]);
            const s16x8 Al = *reinterpret_cast<const s16x8*>(Ab + (afo[q] ^ 64u));
            // ---- stage one half-tile of tile t+2 (issue-early, T3) ----
            if (pf) {
                if (q == 0) {
                    gld16(Ac + aoff[0] + tb2, Sd + ldsoA[0]);
                    gld16(Ac + aoff[1] + tb2, Sd + ldsoA[1]);
                } else if (q == 1) {
                    gld16(Ac + aoff[2] + tb2, Sd + ldsoA[2]);
                    gld16(Ac + aoff[3] + tb2, Sd + ldsoA[3]);
                } else if (q == 2) {
                    gld16(Bc + boff[0] + tb2, Sd + ldsoB[0]);
                    gld16(Bc + boff[1] + tb2, Sd + ldsoB[1]);
                }
            }
            __builtin_amdgcn_s_barrier();
            asm volatile("s_waitcnt lgkmcnt(0)" ::: "memory");
            __builtin_amdgcn_sched_barrier(0);
            __builtin_amdgcn_s_setprio(1);
#pragma unroll
            for (int j = 0; j < 4; ++j) {
                acc[q][j] = __builtin_amdgcn_mfma_f32_16x16x32_bf16(Ah, Bh[j], acc[q][j], 0, 0, 0);
                acc[q][j] = __builtin_amdgcn_mfma_f32_16x16x32_bf16(Al, Bh[j], acc[q][j], 0, 0, 0);
                acc[q][j] = __builtin_amdgcn_mfma_f32_16x16x32_bf16(Ah, Bl[j], acc[q][j], 0, 0, 0);
            }
            __builtin_amdgcn_s_setprio(0);
            if (q == 3 && t + 1 < Kg) {
                if (pf)
                    asm volatile("s_waitcnt vmcnt(6)" ::: "memory");   // T4: counted
                else
                    asm volatile("s_waitcnt vmcnt(0)" ::: "memory");   // tail peel
            }
            __builtin_amdgcn_s_barrier();
        }
        cbuf = (cbuf == 2) ? 0 : cbuf + 1;
        sbuf = (sbuf == 2) ? 0 : sbuf + 1;
    }

    // epilogue: D row = (lane>>4)*4 + reg, col = lane&15 (validated r5/r6)
    float bcol[4];
#pragma unroll
    for (int j = 0; j < 4; ++j)
        bcol[j] = ADDBIAS ? bias[bn + wn + j * 16 + fr] : 0.0f;

#pragma unroll
    for (int i = 0; i < 4; ++i) {
#pragma unroll
        for (int rr = 0; rr < 4; ++rr) {
            const int row = bm + wm + i * 16 + g * 4 + rr;
#pragma unroll
            for (int j = 0; j < 4; ++j) {
                const int col = bn + wn + j * 16 + fr;
                float v = acc[i][j][rr] + bcol[j];
                if (RESID) v += resid[(size_t)row * N + col];
                if (GELU) v = gelu_f(v);
                if (!CONVOUT) {
                    Cout[(size_t)row * N + col] = v;
                } else {
                    const unsigned short h = f2bf(v);
                    const unsigned short l = f2bf(v - bf2f(h));
                    char* p = Cconv +
                              (((size_t)row * (N >> 5) + (col >> 5)) * 8 + ((col >> 3) & 3)) * 16 +
                              (col & 7) * 2;
                    *reinterpret_cast<unsigned short*>(p) = h;
                    *reinterpret_cast<unsigned short*>(p + 64) = l;
                }
            }
        }
    }
}

// ---------------------------------------------------------------------------
// qkv fp32 [B*T][3C] -> bf16 buffers: qb/kb [bh][T][64] (q pre-scaled 1/8),
// vt [bh][64][T] (transposed via LDS). Grid (T/64, B*H), 256 threads.
// ---------------------------------------------------------------------------
__global__ __launch_bounds__(256) void qkv_repack_kernel(
    const float* __restrict__ qkv, unsigned short* __restrict__ qb,
    unsigned short* __restrict__ kb, unsigned short* __restrict__ vtb) {
    const int bh = blockIdx.y;
    const int b = bh >> 4, h = bh & 15;
    const int t0 = blockIdx.x * 64;
    const int tid = threadIdx.x;
    __shared__ unsigned short vtile[64][66];
#pragma unroll
    for (int r = 0; r < 16; ++r) {
        const int idx = tid + r * 256;
        const int t = idx >> 6, d = idx & 63;
        const size_t src = (size_t)(b * Tt + t0 + t) * 3072 + h * 64 + d;
        const size_t dst = ((size_t)bh * Tt + t0 + t) * 64 + d;
        qb[dst] = f2bf(qkv[src] * 0.125f);
        kb[dst] = f2bf(qkv[src + 1024]);
        vtile[t][d] = f2bf(qkv[src + 2048]);
    }
    __syncthreads();
#pragma unroll
    for (int r = 0; r < 16; ++r) {
        const int idx = tid + r * 256;
        const int d = idx >> 6, t = idx & 63;
        vtb[((size_t)bh * 64 + d) * Tt + t0 + t] = vtile[t][d];
    }
}

// ---------------------------------------------------------------------------
// MFMA flash attention (validated r6). Grid (T/64, B*H), 256 threads.
// ---------------------------------------------------------------------------
__global__ __launch_bounds__(256) void attn_mfma_kernel(
    const unsigned short* __restrict__ qbuf, const unsigned short* __restrict__ kbuf,
    const unsigned short* __restrict__ vtbuf, char* __restrict__ yconv) {
    const int qt = blockIdx.x;
    const int bh = blockIdx.y;
    const int tid = threadIdx.x;
    const int w = tid >> 6, lane = tid & 63;
    const int g = lane >> 4, fr = lane & 15;
    const int qbase = qt * 64;

    const unsigned short* Q  = qbuf  + (size_t)bh * Tt * 64;
    const unsigned short* K  = kbuf  + (size_t)bh * Tt * 64;
    const unsigned short* Vt = vtbuf + (size_t)bh * 64 * Tt;

    __shared__ unsigned short Kl[64][72];
    __shared__ unsigned short Vl[64][72];
    __shared__ unsigned short Pl[4][16][72];

    s16x8 qf[2];
#pragma unroll
    for (int s = 0; s < 2; ++s)
        qf[s] = *reinterpret_cast<const s16x8*>(
            &Q[(size_t)(qbase + 16 * w + fr) * 64 + s * 32 + 8 * g]);

    f32x4 acc_o[4];
#pragma unroll
    for (int jd = 0; jd < 4; ++jd) acc_o[jd] = (f32x4)0.0f;
    float lpart[4] = {0.f, 0.f, 0.f, 0.f};

    for (int t0 = 0; t0 <= qt; ++t0) {
        __syncthreads();
#pragma unroll
        for (int r2 = 0; r2 < 2; ++r2) {
            const int idx = tid + r2 * 256;
            const int row = idx >> 3, c = idx & 7;
            *reinterpret_cast<s16x8*>(&Kl[row][c * 8]) =
                *reinterpret_cast<const s16x8*>(&K[(size_t)(t0 * 64 + row) * 64 + c * 8]);
            *reinterpret_cast<s16x8*>(&Vl[row][c * 8]) =
                *reinterpret_cast<const s16x8*>(&Vt[(size_t)row * Tt + t0 * 64 + c * 8]);
        }
        __syncthreads();

        f32x4 acc_s[4];
#pragma unroll
        for (int jk = 0; jk < 4; ++jk) acc_s[jk] = (f32x4)0.0f;
#pragma unroll
        for (int s = 0; s < 2; ++s)
#pragma unroll
            for (int jk = 0; jk < 4; ++jk) {
                const s16x8 kf = *reinterpret_cast<const s16x8*>(
                    &Kl[16 * jk + fr][s * 32 + 8 * g]);
                acc_s[jk] = __builtin_amdgcn_mfma_f32_16x16x32_bf16(qf[s], kf, acc_s[jk], 0, 0, 0);
            }

        const bool diag = (t0 == qt);
#pragma unroll
        for (int jk = 0; jk < 4; ++jk)
#pragma unroll
            for (int rr = 0; rr < 4; ++rr) {
                const int key = 16 * jk + fr;
                const int qrow = 16 * w + 4 * g + rr;
                float p = __expf(acc_s[jk][rr]);
                if (diag && key > qrow) p = 0.0f;
                lpart[rr] += p;
                Pl[w][4 * g + rr][key] = f2bf(p);
            }

#pragma unroll
        for (int s = 0; s < 2; ++s) {
            const s16x8 pf = *reinterpret_cast<const s16x8*>(&Pl[w][fr][s * 32 + 8 * g]);
#pragma unroll
            for (int jd = 0; jd < 4; ++jd) {
                const s16x8 vf = *reinterpret_cast<const s16x8*>(
                    &Vl[16 * jd + fr][s * 32 + 8 * g]);
                acc_o[jd] = __builtin_amdgcn_mfma_f32_16x16x32_bf16(pf, vf, acc_o[jd], 0, 0, 0);
            }
        }
    }

#pragma unroll
    for (int rr = 0; rr < 4; ++rr) {
#pragma unroll
        for (int off = 1; off < 16; off <<= 1)
            lpart[rr] += __shfl_xor(lpart[rr], off);
    }
    float inv[4];
#pragma unroll
    for (int rr = 0; rr < 4; ++rr) inv[rr] = 1.0f / lpart[rr];

    const int bq = bh >> 4;
#pragma unroll
    for (int rr = 0; rr < 4; ++rr) {
        const int row = bq * Tt + qbase + 16 * w + 4 * g + rr;
#pragma unroll
        for (int jd = 0; jd < 4; ++jd) {
            const int col = (bh & 15) * Dh + 16 * jd + fr;
            const float v = acc_o[jd][rr] * inv[rr];
            const unsigned short h = f2bf(v);
            const unsigned short l = f2bf(v - bf2f(h));
            char* p = yconv + (((size_t)row * (Cc >> 5) + (col >> 5)) * 8 + ((col >> 3) & 3)) * 16 +
                      (col & 7) * 2;
            *reinterpret_cast<unsigned short*>(p) = h;
            *reinterpret_cast<unsigned short*>(p + 64) = l;
        }
    }
}

// ---------------------------------------------------------------------------
// Workspace (176 MB, guarded) — unchanged from r6/r7.
// ---------------------------------------------------------------------------
extern "C" void kernel_launch(void* const* d_in, const int* in_sizes, int n_in,
                              void* d_out, int out_size, void* d_ws,
                              size_t ws_size, hipStream_t stream) {
    const float* x      = (const float*)d_in[0];
    const float* w_attn = (const float*)d_in[1];
    const float* b_attn = (const float*)d_in[2];
    const float* w_proj = (const float*)d_in[3];
    const float* b_proj = (const float*)d_in[4];
    const float* w_fc   = (const float*)d_in[5];
    const float* b_fc   = (const float*)d_in[6];
    const float* w_mlp  = (const float*)d_in[7];
    const float* b_mlp  = (const float*)d_in[8];
    float* out = (float*)d_out;

    if (ws_size < (176ull << 20)) return;

    char* ws = (char*)d_ws;
    char*  slotbuf = ws;                                         // 32MB
    float* qkv     = (float*)(ws + (32ull << 20));               // 96MB
    char*  hconv   = ws + (32ull << 20);                         // 128MB overlay
    unsigned short* qb = (unsigned short*)(ws + (128ull << 20)); // 16MB
    unsigned short* kb = (unsigned short*)(ws + (144ull << 20)); // 16MB
    unsigned short* vt = (unsigned short*)(ws + (160ull << 20)); // 16MB
    char*  wscr    = ws + (160ull << 20);                        // 16MB (time-shared with vt)
    float* x1      = out;

    // 1. ln1 -> slotbuf
    ln_conv_kernel<<<Mm, 256, 0, stream>>>(x, slotbuf);
    // 2. qkv = ln1 @ w_attn^T + b_attn (fp32)
    wconv_kernel<<<1536, 256, 0, stream>>>(w_attn, wscr, 3072 * 128, 7, 1024);
    gemm_mfma8<false, false, false, true><<<dim3(24, 32), 512, 0, stream>>>(
        slotbuf, wscr, b_attn, nullptr, qkv, nullptr, Mm, 3 * Cc, Cc);
    // 3. repack qkv -> qb/kb/vt
    qkv_repack_kernel<<<dim3(Tt / 64, Bb * Hh), 256, 0, stream>>>(qkv, qb, kb, vt);
    // 4. attention -> slotbuf (conv)
    attn_mfma_kernel<<<dim3(Tt / 64, Bb * Hh), 256, 0, stream>>>(qb, kb, vt, slotbuf);
    // 5. x1 = x + y @ w_proj^T + b_proj
    wconv_kernel<<<512, 256, 0, stream>>>(w_proj, wscr, 1024 * 128, 7, 1024);
    gemm_mfma8<false, true, false, true><<<dim3(8, 32), 512, 0, stream>>>(
        slotbuf, wscr, b_proj, x, x1, nullptr, Mm, Cc, Cc);
    // 6. ln2 -> slotbuf
    ln_conv_kernel<<<Mm, 256, 0, stream>>>(x1, slotbuf);
    // 7. hconv = gelu(ln2 @ w_fc^T + b_fc)
    wconv_kernel<<<2048, 256, 0, stream>>>(w_fc, wscr, 4096 * 128, 7, 1024);
    gemm_mfma8<true, false, true, true><<<dim3(32, 32), 512, 0, stream>>>(
        slotbuf, wscr, b_fc, nullptr, nullptr, hconv, Mm, 4 * Cc, Cc);
    // 8. out = x1 + h @ w_mlp^T + b_mlp
    wconv_kernel<<<2048, 256, 0, stream>>>(w_mlp, wscr, 1024 * 512, 9, 4096);
    gemm_mfma8<false, true, false, true><<<dim3(8, 32), 512, 0, stream>>>(
        hconv, wscr, b_mlp, x1, out, nullptr, Mm, Cc, 4 * Cc);
}